// Round 3
// baseline (232.888 us; speedup 1.0000x reference)
//
#include <hip/hip_runtime.h>
#include <math.h>
#include <stdint.h>

#define KG 64
#define KG3 (KG * KG * KG)
#define MZK 33  // Hermitian: keep mz in [0,32]
#define ALPHA 0.34f
#define COULOMB 138.935456f
#define CUTOFF2 81.0f
#define PI_F 3.14159265358979323846f
#define DIB 256
#define DJT 32

// ---------------------------------------------------------------- box helpers
struct BoxInfo {
    float inv[9];
    float vol;
    bool diag;
};
__device__ __forceinline__ BoxInfo load_box(const float* __restrict__ box) {
    BoxInfo b;
    float b0 = box[0], b1 = box[1], b2 = box[2];
    float b3 = box[3], b4 = box[4], b5 = box[5];
    float b6 = box[6], b7 = box[7], b8 = box[8];
    float det = b0 * (b4 * b8 - b5 * b7) - b1 * (b3 * b8 - b5 * b6) + b2 * (b3 * b7 - b4 * b6);
    float id = 1.0f / det;
    b.inv[0] = (b4 * b8 - b5 * b7) * id;
    b.inv[1] = (b2 * b7 - b1 * b8) * id;
    b.inv[2] = (b1 * b5 - b2 * b4) * id;
    b.inv[3] = (b5 * b6 - b3 * b8) * id;
    b.inv[4] = (b0 * b8 - b2 * b6) * id;
    b.inv[5] = (b2 * b3 - b0 * b5) * id;
    b.inv[6] = (b3 * b7 - b4 * b6) * id;
    b.inv[7] = (b1 * b6 - b0 * b7) * id;
    b.inv[8] = (b0 * b4 - b1 * b3) * id;
    b.vol = fabsf(det);
    b.diag = (b1 == 0.0f) && (b2 == 0.0f) && (b3 == 0.0f) && (b5 == 0.0f) && (b6 == 0.0f) &&
             (b7 == 0.0f);
    return b;
}

// fast erfc, Abramowitz-Stegun 7.1.26, |abs err| < 1.5e-7 for x >= 0
__device__ __forceinline__ float erfc_fast(float x) {
    float t = __builtin_amdgcn_rcpf(fmaf(0.3275911f, x, 1.0f));
    float p = fmaf(t, 1.061405429f, -1.453152027f);
    p = fmaf(t, p, 1.421413741f);
    p = fmaf(t, p, -0.284496736f);
    p = fmaf(t, p, 0.254829592f);
    return t * p * __expf(-x * x);
}

__device__ __forceinline__ void bspline4(float t, float* w) {
    float w0 = 1.0f - t, w1 = t;
    float a2 = 0.5f * t * w1;
    float a1 = 0.5f * ((t + 1.0f) * w0 + (2.0f - t) * w1);
    float a0 = 0.5f * (1.0f - t) * w0;
    const float d = 1.0f / 3.0f;
    w[3] = d * t * a2;
    w[2] = d * ((t + 1.0f) * a1 + (3.0f - t) * a2);
    w[1] = d * ((t + 2.0f) * a0 + (2.0f - t) * a1);
    w[0] = d * (1.0f - t) * a0;
}

// ---------------------------------------------------------------- DFT twiddles
struct Tw8 {
    float wc[8], ws[8], c8, s8, c1, s1;
};
__device__ __forceinline__ Tw8 make_tw8(int m) {
    Tw8 T;
    float s1, c1;
    __sincosf(-2.0f * PI_F * (float)m / (float)KG, &s1, &c1);
    T.c1 = c1;
    T.s1 = s1;
    float c2 = c1 * c1 - s1 * s1, s2 = 2.0f * c1 * s1;
    float c4 = c2 * c2 - s2 * s2, s4 = 2.0f * c2 * s2;
    T.c8 = c4 * c4 - s4 * s4;
    T.s8 = 2.0f * c4 * s4;
    T.wc[0] = 1.0f;
    T.ws[0] = 0.0f;
    T.wc[1] = c1;
    T.ws[1] = s1;
    T.wc[2] = c2;
    T.ws[2] = s2;
    T.wc[3] = c2 * c1 - s2 * s1;
    T.ws[3] = c2 * s1 + s2 * c1;
    T.wc[4] = c4;
    T.ws[4] = s4;
    T.wc[5] = c4 * c1 - s4 * s1;
    T.ws[5] = c4 * s1 + s4 * c1;
    T.wc[6] = c4 * c2 - s4 * s2;
    T.ws[6] = c4 * s2 + s4 * c2;
    T.wc[7] = c4 * T.wc[3] - s4 * T.ws[3];
    T.ws[7] = c4 * T.ws[3] + s4 * T.wc[3];
    return T;
}

__device__ __forceinline__ float bmod4(float c1, float s1) {
    float c2 = 2.0f * c1 * c1 - 1.0f;
    float s2 = 2.0f * s1 * c1;
    float br = (1.0f + 4.0f * c1 + c2) * (1.0f / 6.0f);
    float bi = (4.0f * s1 + s2) * (1.0f / 6.0f);
    float d2 = br * br + bi * bi;
    return 1.0f / fmaxf(d2, 1e-7f);
}

// ================================================================ spread+direct
// One dispatch, two independent jobs partitioned by block id:
//   blocks [0, DU)        : direct-space tile (ib = (u%nib)*DIB, jb = (u/nib)*DJT)
//   blocks [DU, DU+SB)    : B-spline charge spreading (4 threads/atom)
// Skipped (lower-triangular) direct tiles write partD=0, so no partD memset.
__global__ __launch_bounds__(256) void spread_direct(const float* __restrict__ pos,
                                                     const float* __restrict__ chg,
                                                     const float* __restrict__ box,
                                                     const int* __restrict__ excl, int N, int E,
                                                     float* __restrict__ grid,
                                                     double* __restrict__ partD) {
    int tid = threadIdx.x;
    const int nib = (N + DIB - 1) / DIB;
    const int njt = (N + DJT - 1) / DJT;
    const int DU = nib * njt;
    int u = blockIdx.x;

    if (u >= DU) {
        // ---------------- spread ----------------
        int t4 = (u - DU) * 256 + tid;
        int i = t4 >> 2, jx = t4 & 3;
        if (i >= N) return;
        BoxInfo B = load_box(box);
        float p0 = pos[3 * i], p1 = pos[3 * i + 1], p2 = pos[3 * i + 2];
        float q = chg[i];
        float w[3][4];
        int idx[3][4];
#pragma unroll
        for (int a = 0; a < 3; a++) {
            float f = p0 * B.inv[0 * 3 + a] + p1 * B.inv[1 * 3 + a] + p2 * B.inv[2 * 3 + a];
            f -= floorf(f);
            float uu = f * (float)KG;
            float fu = floorf(uu);
            int base = (int)fu;
            float tt = uu - fu;
            bspline4(tt, w[a]);
#pragma unroll
            for (int j = 0; j < 4; j++) idx[a][j] = (base - 3 + j + 2 * KG) & (KG - 1);
        }
        float qx = q * w[0][jx];
        int bx = idx[0][jx] * KG;
#pragma unroll
        for (int jy = 0; jy < 4; jy++) {
            float qxy = qx * w[1][jy];
            int bxy = (bx + idx[1][jy]) * KG;
#pragma unroll
            for (int jz = 0; jz < 4; jz++) {
                atomicAdd(&grid[bxy + idx[2][jz]], qxy * w[2][jz]);
            }
        }
        return;
    }

    // ---------------- direct ----------------
    int du = u;
    int ib = (du % nib) * DIB, jb = (du / nib) * DJT;
    if (jb + DJT <= ib) {  // fully lower-triangular
        if (tid == 0) partD[du] = 0.0;
        return;
    }

    __shared__ float4 sj[DJT];
    __shared__ double wsum[4];
    if (tid < DJT) {
        int jg0 = jb + tid;
        sj[tid] = (jg0 < N) ? make_float4(pos[3 * jg0], pos[3 * jg0 + 1], pos[3 * jg0 + 2],
                                          chg[jg0])
                            : make_float4(0.0f, 0.0f, 0.0f, 0.0f);
    }
    __syncthreads();

    BoxInfo B = load_box(box);
    double e = 0.0;
    int i = ib + tid;
    if (i < N) {
        float xi = pos[3 * i], yi = pos[3 * i + 1], zi = pos[3 * i + 2], qi = chg[i];
        int ne = (E < 8) ? E : 8;
        int ex[8];
        for (int k = 0; k < ne; k++) ex[k] = excl[i * E + k];

        float fsum = 0.0f;
        if (B.diag) {
            float Lx = box[0], Ly = box[4], Lz = box[8];
            float ivx = B.inv[0], ivy = B.inv[4], ivz = B.inv[8];
#pragma unroll 8
            for (int jj = 0; jj < DJT; jj++) {
                float4 o = sj[jj];
                int jg = jb + jj;
                float dx = xi - o.x, dy = yi - o.y, dz = zi - o.z;
                dx -= rintf(dx * ivx) * Lx;
                dy -= rintf(dy * ivy) * Ly;
                dz -= rintf(dz * ivz) * Lz;
                float r2 = fmaf(dx, dx, fmaf(dy, dy, dz * dz));
                bool valid = (r2 < CUTOFF2) & (jg > i) & (jg < N);
                for (int k = 0; k < ne; k++) valid = valid & (ex[k] != jg);
                float r2m = valid ? r2 : 1.0f;
                float rinv = __builtin_amdgcn_rsqf(r2m);
                float r = r2m * rinv;
                float g = erfc_fast(ALPHA * r) * rinv;
                float qqm = valid ? qi * o.w : 0.0f;
                fsum = fmaf(qqm, g, fsum);
            }
        } else {
#pragma unroll 4
            for (int jj = 0; jj < DJT; jj++) {
                float4 o = sj[jj];
                int jg = jb + jj;
                float dx = xi - o.x, dy = yi - o.y, dz = zi - o.z;
                float s0 = dx * B.inv[0] + dy * B.inv[3] + dz * B.inv[6];
                float s1 = dx * B.inv[1] + dy * B.inv[4] + dz * B.inv[7];
                float s2 = dx * B.inv[2] + dy * B.inv[5] + dz * B.inv[8];
                s0 -= rintf(s0);
                s1 -= rintf(s1);
                s2 -= rintf(s2);
                float ddx = s0 * box[0] + s1 * box[3] + s2 * box[6];
                float ddy = s0 * box[1] + s1 * box[4] + s2 * box[7];
                float ddz = s0 * box[2] + s1 * box[5] + s2 * box[8];
                float r2 = fmaf(ddx, ddx, fmaf(ddy, ddy, ddz * ddz));
                bool valid = (r2 < CUTOFF2) & (jg > i) & (jg < N);
                for (int k = 0; k < ne; k++) valid = valid & (ex[k] != jg);
                float r2m = valid ? r2 : 1.0f;
                float rinv = __builtin_amdgcn_rsqf(r2m);
                float r = r2m * rinv;
                float g = erfc_fast(ALPHA * r) * rinv;
                float qqm = valid ? qi * o.w : 0.0f;
                fsum = fmaf(qqm, g, fsum);
            }
        }
        e = (double)(COULOMB * fsum);

        // one anchor j-tile per i-superblock: self-energy + exclusion corrections
        if (jb == ib) {
            const float inv_sqrt_pi = 0.5641895835477563f;
            float corr = -ALPHA * inv_sqrt_pi * qi * qi;
            for (int k = 0; k < ne; k++) {
                int j = ex[k];
                if (j < 0) continue;
                float ox = pos[3 * j], oy = pos[3 * j + 1], oz = pos[3 * j + 2];
                float qj = chg[j];
                float dx = xi - ox, dy = yi - oy, dz = zi - oz;
                if (B.diag) {
                    dx -= rintf(dx * B.inv[0]) * box[0];
                    dy -= rintf(dy * B.inv[4]) * box[4];
                    dz -= rintf(dz * B.inv[8]) * box[8];
                } else {
                    float s0 = dx * B.inv[0] + dy * B.inv[3] + dz * B.inv[6];
                    float s1 = dx * B.inv[1] + dy * B.inv[4] + dz * B.inv[7];
                    float s2 = dx * B.inv[2] + dy * B.inv[5] + dz * B.inv[8];
                    s0 -= rintf(s0);
                    s1 -= rintf(s1);
                    s2 -= rintf(s2);
                    dx = s0 * box[0] + s1 * box[3] + s2 * box[6];
                    dy = s0 * box[1] + s1 * box[4] + s2 * box[7];
                    dz = s0 * box[2] + s1 * box[5] + s2 * box[8];
                }
                float r2 = dx * dx + dy * dy + dz * dz;
                if (r2 > 0.0f) {
                    float rinv = __builtin_amdgcn_rsqf(r2);
                    float r = r2 * rinv;
                    float erfv = 1.0f - erfc_fast(ALPHA * r);
                    corr += -0.5f * qi * qj * erfv * rinv;
                }
            }
            e += (double)(COULOMB * corr);
        }
    }
#pragma unroll
    for (int off = 32; off > 0; off >>= 1) e += __shfl_down(e, off, 64);
    if ((tid & 63) == 0) wsum[tid >> 6] = e;
    __syncthreads();
    if (tid == 0) partD[du] = wsum[0] + wsum[1] + wsum[2] + wsum[3];
}

// ================================================================ dft_z + dft_y
// One block per x-plane (64 blocks x 512 thr). Plane (64x64 reals) lives in LDS;
// z-DFT then y-DFT with only __syncthreads() between.
// bufB layout [ix][mz][my]: y-pass wave has fixed (ix,mz), lane = my -> each
// wave-store is 64 consecutive float2 = 512 B contiguous (coalesced). This is
// the fix for round-2's 36 MB write amplification (16.9 KB lane stride).
__global__ __launch_bounds__(512) void dft_zy(const float* __restrict__ grid,
                                              float2* __restrict__ bufB) {
    __shared__ float gin[KG * KG];   // [iy*64 + iz]
    __shared__ float zre[KG * MZK];  // [iy*33 + mz], odd stride -> <=2-way banking
    __shared__ float zim[KG * MZK];
    int tid = threadIdx.x, wv = tid >> 6, ln = tid & 63;
    int ix = blockIdx.x;

    // coalesced plane load: 4096 floats = 1024 float4
    const float4* g4 = reinterpret_cast<const float4*>(grid + ix * (KG * KG));
    float4* s4 = reinterpret_cast<float4*>(gin);
#pragma unroll
    for (int k = 0; k < 2; k++) s4[k * 512 + tid] = g4[k * 512 + tid];
    __syncthreads();

    Tw8 T0 = make_tw8(ln);  // lane = output frequency index (mz here, my below)

    // ---- z pass: 64 lines (iy), wave wv handles iy = wv*8 + it
#pragma unroll
    for (int it = 0; it < 8; it++) {
        int iy = wv * 8 + it;
        float wc[8], ws_[8];
#pragma unroll
        for (int g = 0; g < 8; g++) {
            wc[g] = T0.wc[g];
            ws_[g] = T0.ws[g];
        }
        float rr[8] = {0, 0, 0, 0, 0, 0, 0, 0}, ii[8] = {0, 0, 0, 0, 0, 0, 0, 0};
#pragma unroll
        for (int s = 0; s < 8; s++) {
#pragma unroll
            for (int g = 0; g < 8; g++) {
                float gv = gin[iy * KG + s * 8 + g];  // wave-uniform -> LDS broadcast
                rr[g] = fmaf(gv, wc[g], rr[g]);
                ii[g] = fmaf(gv, ws_[g], ii[g]);
                float nc = wc[g] * T0.c8 - ws_[g] * T0.s8;
                ws_[g] = wc[g] * T0.s8 + ws_[g] * T0.c8;
                wc[g] = nc;
            }
        }
        if (ln < MZK) {
            float re = ((rr[0] + rr[1]) + (rr[2] + rr[3])) + ((rr[4] + rr[5]) + (rr[6] + rr[7]));
            float im = ((ii[0] + ii[1]) + (ii[2] + ii[3])) + ((ii[4] + ii[5]) + (ii[6] + ii[7]));
            zre[iy * MZK + ln] = re;
            zim[iy * MZK + ln] = im;
        }
    }
    __syncthreads();

    // ---- y pass: 33 lines (mz), lane = my; coalesced 512B wave-stores
    for (int mz = wv; mz < MZK; mz += 8) {
        float wc[8], ws_[8];
#pragma unroll
        for (int g = 0; g < 8; g++) {
            wc[g] = T0.wc[g];
            ws_[g] = T0.ws[g];
        }
        float rr[8] = {0, 0, 0, 0, 0, 0, 0, 0}, ii[8] = {0, 0, 0, 0, 0, 0, 0, 0};
#pragma unroll
        for (int s = 0; s < 8; s++) {
#pragma unroll
            for (int g = 0; g < 8; g++) {
                int iy = s * 8 + g;
                float ar = zre[iy * MZK + mz];  // wave-uniform -> broadcast
                float ai = zim[iy * MZK + mz];
                rr[g] += ar * wc[g] - ai * ws_[g];
                ii[g] += ar * ws_[g] + ai * wc[g];
                float nc = wc[g] * T0.c8 - ws_[g] * T0.s8;
                ws_[g] = wc[g] * T0.s8 + ws_[g] * T0.c8;
                wc[g] = nc;
            }
        }
        float re = ((rr[0] + rr[1]) + (rr[2] + rr[3])) + ((rr[4] + rr[5]) + (rr[6] + rr[7]));
        float im = ((ii[0] + ii[1]) + (ii[2] + ii[3])) + ((ii[4] + ii[5]) + (ii[6] + ii[7]));
        bufB[(ix * MZK + mz) * KG + ln] = make_float2(re, im);  // ln = my, contiguous
    }
}

// ================================================================ dft_x + reduce
// One block per mz (33 blocks x 512 thr). Loads the [ix][my] tile for its mz
// with contiguous 512B chunks (coalesced), transposes via LDS, computes the
// x-DFT with lane = mx and wave-uniform tile reads (broadcast, conflict-free).
// Influence + partR + last-block-tail deterministic final reduction.
__global__ __launch_bounds__(512) void dft_x_final(const float2* __restrict__ bufB,
                                                   const float* __restrict__ box,
                                                   double* __restrict__ partR,
                                                   const double* __restrict__ parts, int np,
                                                   unsigned* __restrict__ cnt,
                                                   float* __restrict__ out) {
    __shared__ float2 tile[KG][KG];  // [ix][my], 32 KB
    __shared__ double fw[8];
    __shared__ unsigned lastFlag;
    int tid = threadIdx.x, wv = tid >> 6, ln = tid & 63;
    int mz = blockIdx.x;

    // coalesced tile load: wave = one ix row (64 consecutive float2 = 512 B)
#pragma unroll
    for (int rep = 0; rep < 8; rep++) {
        int ix = rep * 8 + wv;
        tile[ix][ln] = bufB[(ix * MZK + mz) * KG + ln];
    }
    __syncthreads();

    BoxInfo B = load_box(box);
    Tw8 T = make_tw8(ln);  // lane = mx
    float bx_ = bmod4(T.c1, T.s1);
    float sz, cz;
    __sincosf(2.0f * PI_F * (float)mz / (float)KG, &sz, &cz);
    float bz_ = bmod4(cz, sz);
    float wgt = (mz == 0 || mz == 32) ? 1.0f : 2.0f;
    float pref = COULOMB / (2.0f * PI_F * B.vol);
    int msz = (mz < KG / 2) ? mz : mz - KG;
    float fmz = (float)msz;
    const float cexp = (PI_F * PI_F) / (ALPHA * ALPHA);
    int msx = (ln < KG / 2) ? ln : ln - KG;
    float fmx = (float)msx;

    // wave wv handles my = wv*8 + it
#pragma unroll
    for (int it = 0; it < 8; it++) {
        int my = wv * 8 + it;
        float wc[8], ws_[8];
#pragma unroll
        for (int g = 0; g < 8; g++) {
            wc[g] = T.wc[g];
            ws_[g] = T.ws[g];
        }
        float rr[8] = {0, 0, 0, 0, 0, 0, 0, 0}, ii[8] = {0, 0, 0, 0, 0, 0, 0, 0};
#pragma unroll
        for (int s = 0; s < 8; s++) {
#pragma unroll
            for (int g = 0; g < 8; g++) {
                float2 a = tile[s * 8 + g][my];  // wave-uniform -> broadcast
                rr[g] += a.x * wc[g] - a.y * ws_[g];
                ii[g] += a.x * ws_[g] + a.y * wc[g];
                float nc = wc[g] * T.c8 - ws_[g] * T.s8;
                ws_[g] = wc[g] * T.s8 + ws_[g] * T.c8;
                wc[g] = nc;
            }
        }
        float re = ((rr[0] + rr[1]) + (rr[2] + rr[3])) + ((rr[4] + rr[5]) + (rr[6] + rr[7]));
        float im = ((ii[0] + ii[1]) + (ii[2] + ii[3])) + ((ii[4] + ii[5]) + (ii[6] + ii[7]));
        float sq = re * re + im * im;

        int msy = (my < KG / 2) ? my : my - KG;
        float fmy = (float)msy;
        float kx = fmx * B.inv[0] + fmy * B.inv[1] + fmz * B.inv[2];
        float ky = fmx * B.inv[3] + fmy * B.inv[4] + fmz * B.inv[5];
        float kz = fmx * B.inv[6] + fmy * B.inv[7] + fmz * B.inv[8];
        float msq = kx * kx + ky * ky + kz * kz;
        float infl = (msq > 0.0f) ? __expf(-cexp * msq) / msq : 0.0f;

        float sy, cy;
        __sincosf(2.0f * PI_F * (float)my / (float)KG, &sy, &cy);
        float by_ = bmod4(cy, sy);

        double term = (double)(wgt * pref * infl * bx_ * by_ * bz_ * sq);
#pragma unroll
        for (int off = 32; off > 0; off >>= 1) term += __shfl_down(term, off, 64);
        if (ln == 0) partR[my * MZK + mz] = term;
    }

    // ---- last-block tail: deterministic final reduction
    __syncthreads();  // drains this block's partR stores
    if (tid == 0) {
        __threadfence();  // release partR to device scope
        unsigned old = atomicAdd(cnt, 1u);
        lastFlag = (old == gridDim.x - 1) ? 1u : 0u;
    }
    __syncthreads();
    if (lastFlag) {
        if (tid == 0) __threadfence();  // acquire
        __syncthreads();
        double s = 0.0;
        for (int k = tid; k < np; k += 512) s += parts[k];
#pragma unroll
        for (int off = 32; off > 0; off >>= 1) s += __shfl_down(s, off, 64);
        if ((tid & 63) == 0) fw[tid >> 6] = s;
        __syncthreads();
        if (tid == 0) {
            double t = 0.0;
#pragma unroll
            for (int w = 0; w < 8; w++) t += fw[w];
            out[0] = (float)t;
        }
    }
}

// ---------------------------------------------------------------- launch

extern "C" void kernel_launch(void* const* d_in, const int* in_sizes, int n_in,
                              void* d_out, int out_size, void* d_ws, size_t ws_size,
                              hipStream_t stream) {
    const float* pos = (const float*)d_in[0];
    const float* chg = (const float*)d_in[1];
    const float* box = (const float*)d_in[2];
    const int* excl = (const int*)d_in[3];
    int N = in_sizes[0] / 3;
    int E = in_sizes[3] / N;

    char* ws = (char*)d_ws;
    // [0]            counter (unsigned)
    // [4096, 20480)  partD: 2048 doubles   [20480, 37376) partR: 2112 doubles
    // [65536, +1MB)  real grid; bufB after it.
    unsigned* cnt = (unsigned*)ws;
    double* partD = (double*)(ws + 4096);
    double* partR = (double*)(ws + 20480);  // == partD + 2048, contiguous
    float* grid = (float*)(ws + 65536);
    float2* bufB = (float2*)(ws + 65536 + 4 * (size_t)KG3);
    float* outp = (float*)d_out;

    const int nib = (N + DIB - 1) / DIB;  // 16
    const int njt = (N + DJT - 1) / DJT;  // 128
    const int DU = nib * njt;             // 2048
    const int SB = (4 * N + 255) / 256;   // 64
    const int np = DU + KG * MZK;         // 2048 + 2112 = 4160

    // 1) zero counter + grid (partD/partR fully written by kernels)
    hipMemsetAsync(ws, 0, 65536 + 4 * (size_t)KG3, stream);

    // 2) direct tiles + spread in one dispatch (independent jobs)
    spread_direct<<<DU + SB, 256, 0, stream>>>(pos, chg, box, excl, N, E, grid, partD);

    // 3) z+y DFT fused per x-plane (coalesced bufB writes)
    dft_zy<<<KG, 512, 0, stream>>>(grid, bufB);

    // 4) x DFT per mz-plane (coalesced reads, LDS transpose) + influence
    //    + last-block final reduction
    dft_x_final<<<MZK, 512, 0, stream>>>(bufB, box, partR, partD, np, cnt, outp);
}

// Round 4
// 124.978 us; speedup vs baseline: 1.8634x; 1.8634x over previous
//
#include <hip/hip_runtime.h>
#include <math.h>
#include <stdint.h>

#define KG 64
#define KG3 (KG * KG * KG)
#define MZK 33  // Hermitian: keep mz in [0,32]
#define ALPHA 0.34f
#define COULOMB 138.935456f
#define CUTOFF2 81.0f
#define PI_F 3.14159265358979323846f
#define DIB 256
#define DJT 32

// ---------------------------------------------------------------- box helpers
struct BoxInfo {
    float inv[9];
    float vol;
    bool diag;
};
__device__ __forceinline__ BoxInfo load_box(const float* __restrict__ box) {
    BoxInfo b;
    float b0 = box[0], b1 = box[1], b2 = box[2];
    float b3 = box[3], b4 = box[4], b5 = box[5];
    float b6 = box[6], b7 = box[7], b8 = box[8];
    float det = b0 * (b4 * b8 - b5 * b7) - b1 * (b3 * b8 - b5 * b6) + b2 * (b3 * b7 - b4 * b6);
    float id = 1.0f / det;
    b.inv[0] = (b4 * b8 - b5 * b7) * id;
    b.inv[1] = (b2 * b7 - b1 * b8) * id;
    b.inv[2] = (b1 * b5 - b2 * b4) * id;
    b.inv[3] = (b5 * b6 - b3 * b8) * id;
    b.inv[4] = (b0 * b8 - b2 * b6) * id;
    b.inv[5] = (b2 * b3 - b0 * b5) * id;
    b.inv[6] = (b3 * b7 - b4 * b6) * id;
    b.inv[7] = (b1 * b6 - b0 * b7) * id;
    b.inv[8] = (b0 * b4 - b1 * b3) * id;
    b.vol = fabsf(det);
    b.diag = (b1 == 0.0f) && (b2 == 0.0f) && (b3 == 0.0f) && (b5 == 0.0f) && (b6 == 0.0f) &&
             (b7 == 0.0f);
    return b;
}

// fast erfc, Abramowitz-Stegun 7.1.26, |abs err| < 1.5e-7 for x >= 0
__device__ __forceinline__ float erfc_fast(float x) {
    float t = __builtin_amdgcn_rcpf(fmaf(0.3275911f, x, 1.0f));
    float p = fmaf(t, 1.061405429f, -1.453152027f);
    p = fmaf(t, p, 1.421413741f);
    p = fmaf(t, p, -0.284496736f);
    p = fmaf(t, p, 0.254829592f);
    return t * p * __expf(-x * x);
}

__device__ __forceinline__ void bspline4(float t, float* w) {
    float w0 = 1.0f - t, w1 = t;
    float a2 = 0.5f * t * w1;
    float a1 = 0.5f * ((t + 1.0f) * w0 + (2.0f - t) * w1);
    float a0 = 0.5f * (1.0f - t) * w0;
    const float d = 1.0f / 3.0f;
    w[3] = d * t * a2;
    w[2] = d * ((t + 1.0f) * a1 + (3.0f - t) * a2);
    w[1] = d * ((t + 2.0f) * a0 + (2.0f - t) * a1);
    w[0] = d * (1.0f - t) * a0;
}

// ---------------------------------------------------------------- DFT twiddles
struct Tw8 {
    float wc[8], ws[8], c8, s8, c1, s1;
};
__device__ __forceinline__ Tw8 make_tw8(int m) {
    Tw8 T;
    float s1, c1;
    __sincosf(-2.0f * PI_F * (float)m / (float)KG, &s1, &c1);
    T.c1 = c1;
    T.s1 = s1;
    float c2 = c1 * c1 - s1 * s1, s2 = 2.0f * c1 * s1;
    float c4 = c2 * c2 - s2 * s2, s4 = 2.0f * c2 * s2;
    T.c8 = c4 * c4 - s4 * s4;
    T.s8 = 2.0f * c4 * s4;
    T.wc[0] = 1.0f;
    T.ws[0] = 0.0f;
    T.wc[1] = c1;
    T.ws[1] = s1;
    T.wc[2] = c2;
    T.ws[2] = s2;
    T.wc[3] = c2 * c1 - s2 * s1;
    T.ws[3] = c2 * s1 + s2 * c1;
    T.wc[4] = c4;
    T.ws[4] = s4;
    T.wc[5] = c4 * c1 - s4 * s1;
    T.ws[5] = c4 * s1 + s4 * c1;
    T.wc[6] = c4 * c2 - s4 * s2;
    T.ws[6] = c4 * s2 + s4 * c2;
    T.wc[7] = c4 * T.wc[3] - s4 * T.ws[3];
    T.ws[7] = c4 * T.ws[3] + s4 * T.wc[3];
    return T;
}

__device__ __forceinline__ float bmod4(float c1, float s1) {
    float c2 = 2.0f * c1 * c1 - 1.0f;
    float s2 = 2.0f * s1 * c1;
    float br = (1.0f + 4.0f * c1 + c2) * (1.0f / 6.0f);
    float bi = (4.0f * s1 + s2) * (1.0f / 6.0f);
    float d2 = br * br + bi * bi;
    return 1.0f / fmaxf(d2, 1e-7f);
}

// ================================================================ spread+direct
// One dispatch, two independent jobs partitioned by block id (both wide):
//   blocks [0, DU)     : direct-space tile (ib = (u%nib)*DIB, jb = (u/nib)*DJT)
//   blocks [DU, DU+SB) : B-spline charge spreading (4 threads/atom)
// Skipped (lower-triangular) direct tiles write partD=0, so no partD memset.
__global__ __launch_bounds__(256) void spread_direct(const float* __restrict__ pos,
                                                     const float* __restrict__ chg,
                                                     const float* __restrict__ box,
                                                     const int* __restrict__ excl, int N, int E,
                                                     float* __restrict__ grid,
                                                     double* __restrict__ partD) {
    int tid = threadIdx.x;
    const int nib = (N + DIB - 1) / DIB;
    const int njt = (N + DJT - 1) / DJT;
    const int DU = nib * njt;
    int u = blockIdx.x;

    if (u >= DU) {
        // ---------------- spread ----------------
        int t4 = (u - DU) * 256 + tid;
        int i = t4 >> 2, jx = t4 & 3;
        if (i >= N) return;
        BoxInfo B = load_box(box);
        float p0 = pos[3 * i], p1 = pos[3 * i + 1], p2 = pos[3 * i + 2];
        float q = chg[i];
        float w[3][4];
        int idx[3][4];
#pragma unroll
        for (int a = 0; a < 3; a++) {
            float f = p0 * B.inv[0 * 3 + a] + p1 * B.inv[1 * 3 + a] + p2 * B.inv[2 * 3 + a];
            f -= floorf(f);
            float uu = f * (float)KG;
            float fu = floorf(uu);
            int base = (int)fu;
            float tt = uu - fu;
            bspline4(tt, w[a]);
#pragma unroll
            for (int j = 0; j < 4; j++) idx[a][j] = (base - 3 + j + 2 * KG) & (KG - 1);
        }
        float qx = q * w[0][jx];
        int bx = idx[0][jx] * KG;
#pragma unroll
        for (int jy = 0; jy < 4; jy++) {
            float qxy = qx * w[1][jy];
            int bxy = (bx + idx[1][jy]) * KG;
#pragma unroll
            for (int jz = 0; jz < 4; jz++) {
                atomicAdd(&grid[bxy + idx[2][jz]], qxy * w[2][jz]);
            }
        }
        return;
    }

    // ---------------- direct ----------------
    int du = u;
    int ib = (du % nib) * DIB, jb = (du / nib) * DJT;
    if (jb + DJT <= ib) {  // fully lower-triangular
        if (tid == 0) partD[du] = 0.0;
        return;
    }

    __shared__ float4 sj[DJT];
    __shared__ double wsum[4];
    if (tid < DJT) {
        int jg0 = jb + tid;
        sj[tid] = (jg0 < N) ? make_float4(pos[3 * jg0], pos[3 * jg0 + 1], pos[3 * jg0 + 2],
                                          chg[jg0])
                            : make_float4(0.0f, 0.0f, 0.0f, 0.0f);
    }
    __syncthreads();

    BoxInfo B = load_box(box);
    double e = 0.0;
    int i = ib + tid;
    if (i < N) {
        float xi = pos[3 * i], yi = pos[3 * i + 1], zi = pos[3 * i + 2], qi = chg[i];
        int ne = (E < 8) ? E : 8;
        int ex[8];
        for (int k = 0; k < ne; k++) ex[k] = excl[i * E + k];

        float fsum = 0.0f;
        if (B.diag) {
            float Lx = box[0], Ly = box[4], Lz = box[8];
            float ivx = B.inv[0], ivy = B.inv[4], ivz = B.inv[8];
#pragma unroll 8
            for (int jj = 0; jj < DJT; jj++) {
                float4 o = sj[jj];
                int jg = jb + jj;
                float dx = xi - o.x, dy = yi - o.y, dz = zi - o.z;
                dx -= rintf(dx * ivx) * Lx;
                dy -= rintf(dy * ivy) * Ly;
                dz -= rintf(dz * ivz) * Lz;
                float r2 = fmaf(dx, dx, fmaf(dy, dy, dz * dz));
                bool valid = (r2 < CUTOFF2) & (jg > i) & (jg < N);
                for (int k = 0; k < ne; k++) valid = valid & (ex[k] != jg);
                float r2m = valid ? r2 : 1.0f;
                float rinv = __builtin_amdgcn_rsqf(r2m);
                float r = r2m * rinv;
                float g = erfc_fast(ALPHA * r) * rinv;
                float qqm = valid ? qi * o.w : 0.0f;
                fsum = fmaf(qqm, g, fsum);
            }
        } else {
#pragma unroll 4
            for (int jj = 0; jj < DJT; jj++) {
                float4 o = sj[jj];
                int jg = jb + jj;
                float dx = xi - o.x, dy = yi - o.y, dz = zi - o.z;
                float s0 = dx * B.inv[0] + dy * B.inv[3] + dz * B.inv[6];
                float s1 = dx * B.inv[1] + dy * B.inv[4] + dz * B.inv[7];
                float s2 = dx * B.inv[2] + dy * B.inv[5] + dz * B.inv[8];
                s0 -= rintf(s0);
                s1 -= rintf(s1);
                s2 -= rintf(s2);
                float ddx = s0 * box[0] + s1 * box[3] + s2 * box[6];
                float ddy = s0 * box[1] + s1 * box[4] + s2 * box[7];
                float ddz = s0 * box[2] + s1 * box[5] + s2 * box[8];
                float r2 = fmaf(ddx, ddx, fmaf(ddy, ddy, ddz * ddz));
                bool valid = (r2 < CUTOFF2) & (jg > i) & (jg < N);
                for (int k = 0; k < ne; k++) valid = valid & (ex[k] != jg);
                float r2m = valid ? r2 : 1.0f;
                float rinv = __builtin_amdgcn_rsqf(r2m);
                float r = r2m * rinv;
                float g = erfc_fast(ALPHA * r) * rinv;
                float qqm = valid ? qi * o.w : 0.0f;
                fsum = fmaf(qqm, g, fsum);
            }
        }
        e = (double)(COULOMB * fsum);

        // one anchor j-tile per i-superblock: self-energy + exclusion corrections
        if (jb == ib) {
            const float inv_sqrt_pi = 0.5641895835477563f;
            float corr = -ALPHA * inv_sqrt_pi * qi * qi;
            for (int k = 0; k < ne; k++) {
                int j = ex[k];
                if (j < 0) continue;
                float ox = pos[3 * j], oy = pos[3 * j + 1], oz = pos[3 * j + 2];
                float qj = chg[j];
                float dx = xi - ox, dy = yi - oy, dz = zi - oz;
                if (B.diag) {
                    dx -= rintf(dx * B.inv[0]) * box[0];
                    dy -= rintf(dy * B.inv[4]) * box[4];
                    dz -= rintf(dz * B.inv[8]) * box[8];
                } else {
                    float s0 = dx * B.inv[0] + dy * B.inv[3] + dz * B.inv[6];
                    float s1 = dx * B.inv[1] + dy * B.inv[4] + dz * B.inv[7];
                    float s2 = dx * B.inv[2] + dy * B.inv[5] + dz * B.inv[8];
                    s0 -= rintf(s0);
                    s1 -= rintf(s1);
                    s2 -= rintf(s2);
                    dx = s0 * box[0] + s1 * box[3] + s2 * box[6];
                    dy = s0 * box[1] + s1 * box[4] + s2 * box[7];
                    dz = s0 * box[2] + s1 * box[5] + s2 * box[8];
                }
                float r2 = dx * dx + dy * dy + dz * dz;
                if (r2 > 0.0f) {
                    float rinv = __builtin_amdgcn_rsqf(r2);
                    float r = r2 * rinv;
                    float erfv = 1.0f - erfc_fast(ALPHA * r);
                    corr += -0.5f * qi * qj * erfv * rinv;
                }
            }
            e += (double)(COULOMB * corr);
        }
    }
#pragma unroll
    for (int off = 32; off > 0; off >>= 1) e += __shfl_down(e, off, 64);
    if ((tid & 63) == 0) wsum[tid >> 6] = e;
    __syncthreads();
    if (tid == 0) partD[du] = wsum[0] + wsum[1] + wsum[2] + wsum[3];
}

// ================================================================ 3-pass DFT
// Wide grids (1024 / 528 / 528 blocks): round-0 structure, proven <40us/stage.
// pass 1: real grid[ix][iy][iz] -> bufA[ix][mz][iy], mz<=32 only.
__global__ __launch_bounds__(256) void dft_z(const float* __restrict__ grid,
                                             float2* __restrict__ bufA) {
    __shared__ float g[4][KG];
    int tid = threadIdx.x, wv = tid >> 6, ln = tid & 63;
    int line = blockIdx.x * 4 + wv;  // ix*KG + iy
    g[wv][ln] = grid[line * KG + ln];
    __syncthreads();
    Tw8 T = make_tw8(ln);
    float rr[8] = {0}, ii[8] = {0};
#pragma unroll
    for (int s = 0; s < 8; s++) {
#pragma unroll
        for (int gg = 0; gg < 8; gg++) {
            float gv = g[wv][s * 8 + gg];
            rr[gg] = fmaf(gv, T.wc[gg], rr[gg]);
            ii[gg] = fmaf(gv, T.ws[gg], ii[gg]);
            float nc = T.wc[gg] * T.c8 - T.ws[gg] * T.s8;
            T.ws[gg] = T.wc[gg] * T.s8 + T.ws[gg] * T.c8;
            T.wc[gg] = nc;
        }
    }
    if (ln < MZK) {
        float re = ((rr[0] + rr[1]) + (rr[2] + rr[3])) + ((rr[4] + rr[5]) + (rr[6] + rr[7]));
        float im = ((ii[0] + ii[1]) + (ii[2] + ii[3])) + ((ii[4] + ii[5]) + (ii[6] + ii[7]));
        int ix = line >> 6, iy = line & 63;
        bufA[(ix * KG + ln) * KG + iy] = make_float2(re, im);
    }
}

// pass 2: bufA[ix][mz][iy] -> bufB[my][mz][ix], lines = (ix, mz in [0,33))
__global__ __launch_bounds__(256) void dft_y(const float2* __restrict__ bufA,
                                             float2* __restrict__ bufB) {
    __shared__ float2 c[4][KG];
    int tid = threadIdx.x, wv = tid >> 6, ln = tid & 63;
    int idx = blockIdx.x * 4 + wv;
    if (idx >= KG * MZK) return;
    int ix = idx / MZK, mz = idx - ix * MZK;
    c[wv][ln] = bufA[(ix * KG + mz) * KG + ln];
    __syncthreads();
    Tw8 T = make_tw8(ln);
    float rr[8] = {0}, ii[8] = {0};
#pragma unroll
    for (int s = 0; s < 8; s++) {
#pragma unroll
        for (int gg = 0; gg < 8; gg++) {
            float2 a = c[wv][s * 8 + gg];
            rr[gg] += a.x * T.wc[gg] - a.y * T.ws[gg];
            ii[gg] += a.x * T.ws[gg] + a.y * T.wc[gg];
            float nc = T.wc[gg] * T.c8 - T.ws[gg] * T.s8;
            T.ws[gg] = T.wc[gg] * T.s8 + T.ws[gg] * T.c8;
            T.wc[gg] = nc;
        }
    }
    float re = ((rr[0] + rr[1]) + (rr[2] + rr[3])) + ((rr[4] + rr[5]) + (rr[6] + rr[7]));
    float im = ((ii[0] + ii[1]) + (ii[2] + ii[3])) + ((ii[4] + ii[5]) + (ii[6] + ii[7]));
    bufB[(ln * MZK + mz) * KG + ix] = make_float2(re, im);
}

// pass 3 + influence + last-block tail reduction. bufB[my][mz][ix], lane = mx.
// Hermitian weight: 2 for mz in [1,31], 1 for mz = 0, 32.
__global__ __launch_bounds__(256) void dft_x_final(const float2* __restrict__ bufB,
                                                   const float* __restrict__ box,
                                                   double* __restrict__ partR,
                                                   const double* __restrict__ parts, int np,
                                                   unsigned* __restrict__ cnt,
                                                   float* __restrict__ out) {
    __shared__ float2 c[4][KG];
    __shared__ double fw[4];
    __shared__ unsigned lastFlag;
    int tid = threadIdx.x, wv = tid >> 6, ln = tid & 63;
    int idx = blockIdx.x * 4 + wv;
    int my = idx / MZK, mz = idx - my * MZK;
    c[wv][ln] = bufB[(my * MZK + mz) * KG + ln];
    __syncthreads();
    Tw8 T = make_tw8(ln);
    float rr[8] = {0}, ii[8] = {0};
#pragma unroll
    for (int s = 0; s < 8; s++) {
#pragma unroll
        for (int gg = 0; gg < 8; gg++) {
            float2 a = c[wv][s * 8 + gg];
            rr[gg] += a.x * T.wc[gg] - a.y * T.ws[gg];
            ii[gg] += a.x * T.ws[gg] + a.y * T.wc[gg];
            float nc = T.wc[gg] * T.c8 - T.ws[gg] * T.s8;
            T.ws[gg] = T.wc[gg] * T.s8 + T.ws[gg] * T.c8;
            T.wc[gg] = nc;
        }
    }
    float re = ((rr[0] + rr[1]) + (rr[2] + rr[3])) + ((rr[4] + rr[5]) + (rr[6] + rr[7]));
    float im = ((ii[0] + ii[1]) + (ii[2] + ii[3])) + ((ii[4] + ii[5]) + (ii[6] + ii[7]));
    float sq = re * re + im * im;

    BoxInfo B = load_box(box);
    int mx = ln;
    int msx = (mx < KG / 2) ? mx : mx - KG;
    int msy = (my < KG / 2) ? my : my - KG;
    int msz = (mz < KG / 2) ? mz : mz - KG;
    float fmx = (float)msx, fmy = (float)msy, fmz = (float)msz;
    float kx = fmx * B.inv[0] + fmy * B.inv[1] + fmz * B.inv[2];
    float ky = fmx * B.inv[3] + fmy * B.inv[4] + fmz * B.inv[5];
    float kz = fmx * B.inv[6] + fmy * B.inv[7] + fmz * B.inv[8];
    float msq = kx * kx + ky * ky + kz * kz;
    const float cexp = (PI_F * PI_F) / (ALPHA * ALPHA);
    float infl = (msq > 0.0f) ? __expf(-cexp * msq) / msq : 0.0f;

    float bx_ = bmod4(T.c1, T.s1);
    float sy, cy, sz, cz;
    __sincosf(2.0f * PI_F * (float)my / (float)KG, &sy, &cy);
    __sincosf(2.0f * PI_F * (float)mz / (float)KG, &sz, &cz);
    float by_ = bmod4(cy, sy);
    float bz_ = bmod4(cz, sz);

    float wgt = (mz == 0 || mz == 32) ? 1.0f : 2.0f;
    float pref = COULOMB / (2.0f * PI_F * B.vol);
    double term = (double)(wgt * pref * infl * bx_ * by_ * bz_ * sq);

#pragma unroll
    for (int off = 32; off > 0; off >>= 1) term += __shfl_down(term, off, 64);
    if (ln == 0) partR[idx] = term;

    // ---- last-block tail: deterministic final reduction (saves a dispatch)
    __syncthreads();  // drains this block's partR stores
    if (tid == 0) {
        __threadfence();  // release partR to device scope
        unsigned old = atomicAdd(cnt, 1u);
        lastFlag = (old == gridDim.x - 1) ? 1u : 0u;
    }
    __syncthreads();
    if (lastFlag) {
        if (tid == 0) __threadfence();  // acquire
        __syncthreads();
        double s = 0.0;
        for (int k = tid; k < np; k += 256) s += parts[k];
#pragma unroll
        for (int off = 32; off > 0; off >>= 1) s += __shfl_down(s, off, 64);
        if ((tid & 63) == 0) fw[tid >> 6] = s;
        __syncthreads();
        if (tid == 0) out[0] = (float)(fw[0] + fw[1] + fw[2] + fw[3]);
    }
}

// ---------------------------------------------------------------- launch

extern "C" void kernel_launch(void* const* d_in, const int* in_sizes, int n_in,
                              void* d_out, int out_size, void* d_ws, size_t ws_size,
                              hipStream_t stream) {
    const float* pos = (const float*)d_in[0];
    const float* chg = (const float*)d_in[1];
    const float* box = (const float*)d_in[2];
    const int* excl = (const int*)d_in[3];
    int N = in_sizes[0] / 3;
    int E = in_sizes[3] / N;

    char* ws = (char*)d_ws;
    // [0]            counter (unsigned)
    // [4096, 20480)  partD: 2048 doubles   [20480, 37376) partR: 2112 doubles
    // [65536, +1MB)  real grid; bufA (2MB region) @ +4*KG3; bufB @ +12*KG3.
    unsigned* cnt = (unsigned*)ws;
    double* partD = (double*)(ws + 4096);
    double* partR = (double*)(ws + 20480);  // == partD + 2048, contiguous
    float* grid = (float*)(ws + 65536);
    float2* bufA = (float2*)(ws + 65536 + 4 * (size_t)KG3);
    float2* bufB = (float2*)(ws + 65536 + 12 * (size_t)KG3);
    float* outp = (float*)d_out;

    const int nib = (N + DIB - 1) / DIB;  // 16
    const int njt = (N + DJT - 1) / DJT;  // 128
    const int DU = nib * njt;             // 2048
    const int SB = (4 * N + 255) / 256;   // 64
    const int nlines = KG * MZK;          // 2112
    const int np = DU + nlines;           // 4160

    // 1) zero counter + grid (partD/partR fully written by kernels)
    hipMemsetAsync(ws, 0, 65536 + 4 * (size_t)KG3, stream);

    // 2) direct tiles + spread in one dispatch (independent, wide: 2112 blocks)
    spread_direct<<<DU + SB, 256, 0, stream>>>(pos, chg, box, excl, N, E, grid, partD);

    // 3) wide 3-pass DFT (1024 / 528 / 528 blocks)
    dft_z<<<KG * KG / 4, 256, 0, stream>>>(grid, bufA);
    dft_y<<<(nlines + 3) / 4, 256, 0, stream>>>(bufA, bufB);
    dft_x_final<<<(nlines + 3) / 4, 256, 0, stream>>>(bufB, box, partR, partD, np, cnt, outp);
}